// Round 15
// baseline (769.489 us; speedup 1.0000x reference)
//
#include <hip/hip_runtime.h>
#include <hip/hip_cooperative_groups.h>
#include <cstdint>
#include <cstddef>

namespace cg = cooperative_groups;

#define DFEAT 64
#define LSLOPE 0.01f
#define BINSHIFT 9          // 512 nodes per bin
#define BINCAP 6144         // mean ~5120 edges/bin, +14 sigma margin
#define CHUNK 4096

typedef _Float16 h8 __attribute__((ext_vector_type(8)));
typedef _Float16 h4 __attribute__((ext_vector_type(4)));
typedef _Float16 h2 __attribute__((ext_vector_type(2)));
typedef float f4 __attribute__((ext_vector_type(4)));

// ---------------------------------------------------------------- setup
__global__ void setup_kernel(const unsigned int* __restrict__ ei, int* flag,
                             int* __restrict__ binCnt) {
  __shared__ int cnt;
  if (threadIdx.x == 0) cnt = 0;
  binCnt[threadIdx.x] = 0;
  __syncthreads();
  int z = 0;
  for (int i = threadIdx.x; i < 1024; i += blockDim.x)
    z += (ei[2 * i + 1] == 0u) ? 1 : 0;
  atomicAdd(&cnt, z);
  __syncthreads();
  if (threadIdx.x == 0) *flag = (cnt == 1024) ? 1 : 0;
}

// ---------------------------------------------------------------- cvt + W-prep
__global__ void cvtprep_kernel(const float* __restrict__ in, _Float16* __restrict__ out,
                               int n4, const float* __restrict__ W1,
                               const float* __restrict__ W2, _Float16* __restrict__ Wt) {
  int i = blockIdx.x * blockDim.x + threadIdx.x;
  if (i < n4) {
    float4 v = ((const float4*)in)[i];
    h4 o;
    o[0] = (_Float16)v.x; o[1] = (_Float16)v.y;
    o[2] = (_Float16)v.z; o[3] = (_Float16)v.w;
    ((h4*)out)[i] = o;
  } else {
    int t = i - n4;
    if (t < 2 * 64 * 264) {
      int layer = t / (64 * 264);
      int r = t % (64 * 264);
      int c = r / 264;
      int kg = r % 264;
      float v = 0.f;
      if (kg < 256) {
        const float* W = layer ? W2 : W1;
        int a = kg >> 6, k = kg & 63;
        v = W[a * 4096 + k * 64 + c];
      }
      Wt[t] = (_Float16)v;
    }
  }
}

// ---------------------------------------------------------------- binned CSR build
__global__ __launch_bounds__(256) void binA_kernel(
    const void* __restrict__ ei, const float* __restrict__ ew, int E,
    const int* __restrict__ flag, int* __restrict__ binCnt,
    int2* __restrict__ bins, int nbins) {
  __shared__ int hist[256];
  __shared__ int pref[256];
  __shared__ int lofs[256];
  __shared__ int gbase[256];
  __shared__ int2 pairs[CHUNK];   // 32 KB
  int tid = threadIdx.x;
  int base = blockIdx.x * CHUNK;
  int nedge = E - base; if (nedge > CHUNK) nedge = CHUNK;
  for (int i = tid; i < nbins; i += 256) hist[i] = 0;
  __syncthreads();
  const bool is64 = (*flag != 0);
  for (int j = tid; j < nedge; j += 256) {
    int e = base + j;
    int d = is64 ? (int)((const long long*)ei)[(size_t)E + e]
                 : ((const int*)ei)[(size_t)E + e];
    atomicAdd(&hist[d >> BINSHIFT], 1);
  }
  __syncthreads();
  if (tid == 0) {
    int run = 0;
    for (int b = 0; b < nbins; ++b) { pref[b] = run; lofs[b] = run; run += hist[b]; }
  }
  __syncthreads();
  for (int j = tid; j < nedge; j += 256) {
    int e = base + j;
    int s, d;
    if (is64) { const long long* p = (const long long*)ei; s = (int)p[e]; d = (int)p[(size_t)E + e]; }
    else      { const int* p = (const int*)ei; s = p[e]; d = p[(size_t)E + e]; }
    int wq = (int)(ew[e] * 32768.0f + 0.5f);
    wq = wq > 32767 ? 32767 : wq;
    unsigned P = ((unsigned)s << 15) | (unsigned)wq;
    int pos = atomicAdd(&lofs[d >> BINSHIFT], 1);
    pairs[pos] = make_int2((int)P, d);
  }
  __syncthreads();
  for (int b = tid; b < nbins; b += 256)
    gbase[b] = (hist[b] > 0) ? atomicAdd(&binCnt[b], hist[b]) : 0;
  __syncthreads();
  for (int i = tid; i < nedge; i += 256) {
    int2 pr = pairs[i];
    int b = pr.y >> BINSHIFT;
    int off = gbase[b] + (i - pref[b]);
    if (off < BINCAP) bins[(size_t)b * BINCAP + off] = pr;
  }
}

__global__ __launch_bounds__(256) void binB_kernel(
    const int2* __restrict__ bins, const int* __restrict__ binCnt,
    int* __restrict__ rowptr, unsigned* __restrict__ ep, int nbins, int N) {
  __shared__ int ssum[256];
  __shared__ int cnt[512];
  __shared__ int ofs[512];
  int b = blockIdx.x, tid = threadIdx.x;
  ssum[tid] = (tid < nbins) ? binCnt[tid] : 0;
  __syncthreads();
  for (int off = 1; off < 256; off <<= 1) {
    int val = ssum[tid];
    int add = (tid >= off) ? ssum[tid - off] : 0;
    __syncthreads();
    ssum[tid] = val + add;
    __syncthreads();
  }
  int gstart = (b == 0) ? 0 : ssum[b - 1];
  if (b == nbins - 1 && tid == 0) rowptr[N] = ssum[nbins - 1];
  int nb = binCnt[b]; if (nb > BINCAP) nb = BINCAP;
  int dstBase = b << BINSHIFT;
  const int2* mybin = bins + (size_t)b * BINCAP;
  for (int i = tid; i < 512; i += 256) cnt[i] = 0;
  __syncthreads();
  for (int i = tid; i < nb; i += 256)
    atomicAdd(&cnt[mybin[i].y & 511], 1);
  __syncthreads();
  if (tid == 0) {
    int run = gstart;
    for (int k = 0; k < 512; ++k) { ofs[k] = run; run += cnt[k]; }
  }
  __syncthreads();
  for (int k = tid; k < 512; k += 256) {
    int d = dstBase + k;
    if (d < N) rowptr[d] = ofs[k];
  }
  __syncthreads();
  for (int i = tid; i < nb; i += 256) {
    int2 pr = mybin[i];
    int pos = atomicAdd(&ofs[pr.y & 511], 1);
    ep[pos] = (unsigned)pr.x;
  }
}

// ---------------------------------------------------------------- SpMM core (r13)
__device__ __forceinline__ void edge_fma(unsigned p, const uint4& v, float qs,
                                         h2& acc0, h2& acc1, h2& acc2, h2& acc3) {
  _Float16 wh = (_Float16)((float)(p & 32767u) * qs);
  h2 wp = {wh, wh};
  union { uint32_t u; h2 h; } cx, cy, cz, cw;
  cx.u = v.x; cy.u = v.y; cz.u = v.z; cw.u = v.w;
  acc0 += wp * cx.h; acc1 += wp * cy.h;
  acc2 += wp * cz.h; acc3 += wp * cw.h;
}

__device__ __forceinline__ uint4 spmm_node(const uint4* __restrict__ xu,
                                           const unsigned* __restrict__ ep,
                                           int beg, int end, int fo) {
  const float qs = 1.0f / 32768.0f;
  h2 acc0 = {0, 0}, acc1 = {0, 0}, acc2 = {0, 0}, acc3 = {0, 0};
  int n = end - beg;
  if (n >= 4) {
    unsigned pa = ep[beg], pb = ep[beg + 1], pc = ep[beg + 2], pd = ep[beg + 3];
    uint4 va = xu[(size_t)(pa >> 15) * 8 + fo];
    uint4 vb = xu[(size_t)(pb >> 15) * 8 + fo];
    uint4 vc = xu[(size_t)(pc >> 15) * 8 + fo];
    uint4 vd = xu[(size_t)(pd >> 15) * 8 + fo];
    int i = beg + 4;
    for (; i + 3 < end; i += 4) {
      edge_fma(pa, va, qs, acc0, acc1, acc2, acc3);
      pa = ep[i];     va = xu[(size_t)(pa >> 15) * 8 + fo];
      edge_fma(pb, vb, qs, acc0, acc1, acc2, acc3);
      pb = ep[i + 1]; vb = xu[(size_t)(pb >> 15) * 8 + fo];
      edge_fma(pc, vc, qs, acc0, acc1, acc2, acc3);
      pc = ep[i + 2]; vc = xu[(size_t)(pc >> 15) * 8 + fo];
      edge_fma(pd, vd, qs, acc0, acc1, acc2, acc3);
      pd = ep[i + 3]; vd = xu[(size_t)(pd >> 15) * 8 + fo];
    }
    edge_fma(pa, va, qs, acc0, acc1, acc2, acc3);
    edge_fma(pb, vb, qs, acc0, acc1, acc2, acc3);
    edge_fma(pc, vc, qs, acc0, acc1, acc2, acc3);
    edge_fma(pd, vd, qs, acc0, acc1, acc2, acc3);
    for (; i < end; ++i) {
      unsigned p = ep[i];
      uint4 v = xu[(size_t)(p >> 15) * 8 + fo];
      edge_fma(p, v, qs, acc0, acc1, acc2, acc3);
    }
  } else {
    for (int i = beg; i < end; ++i) {
      unsigned p = ep[i];
      uint4 v = xu[(size_t)(p >> 15) * 8 + fo];
      edge_fma(p, v, qs, acc0, acc1, acc2, acc3);
    }
  }
  union { uint4 u; h2 h[4]; } o;
  o.h[0] = acc0; o.h[1] = acc1; o.h[2] = acc2; o.h[3] = acc3;
  return o.u;
}

// grid-stride spmm phase (no early returns -- all threads reach grid.sync)
__device__ __forceinline__ void spmm_phase(const _Float16* __restrict__ x,
                                           const int* __restrict__ rowptr,
                                           const unsigned* __restrict__ ep,
                                           _Float16* __restrict__ hout, int N) {
  int fo = threadIdx.x & 7;
  int lid = threadIdx.x >> 3;
  for (long long base = (long long)blockIdx.x * 32; base < N;
       base += (long long)gridDim.x * 32) {
    long long node = base + lid;
    if (node < N) {
      uint4 r = spmm_node((const uint4*)x, ep, rowptr[node], rowptr[node + 1], fo);
      ((uint4*)hout)[node * 8 + fo] = r;
    }
  }
}

// grid-stride combine phase (r13 combine body; W staged to LDS per phase)
template <int OUTF16>
__device__ __forceinline__ void combine_phase(
    _Float16* __restrict__ Wl,
    const _Float16* __restrict__ x0, const _Float16* __restrict__ h1,
    const _Float16* __restrict__ h2v, const _Float16* __restrict__ h3,
    const _Float16* __restrict__ Wt, const float* __restrict__ b,
    const _Float16* __restrict__ resid, void* __restrict__ outp, int N) {
  int tid = threadIdx.x;
  {
    const uint32_t* g = (const uint32_t*)Wt;
    uint32_t* l = (uint32_t*)Wl;
    for (int i = tid; i < 64 * 132; i += 256) l[i] = g[i];
  }
  __syncthreads();

  int w = tid >> 6, lane = tid & 63;
  int l16 = lane & 15, lq = lane >> 4;
  const _Float16* hops[4] = {x0, h1, h2v, h3};

  for (long long t0 = (long long)blockIdx.x * 128; t0 < N;
       t0 += (long long)gridDim.x * 128) {
    long long r0 = t0 + w * 32;

    f4 acc[2][4];
    f4 zero = {0.f, 0.f, 0.f, 0.f};
    #pragma unroll
    for (int rt = 0; rt < 2; ++rt)
      #pragma unroll
      for (int ct = 0; ct < 4; ++ct) acc[rt][ct] = zero;

    #pragma unroll
    for (int s = 0; s < 8; ++s) {
      const _Float16* __restrict__ Xa = hops[s >> 1];
      int kk = ((s & 1) << 5) + (lq << 3);
      long long ra = r0 + l16;
      long long rb = ra + 16;
      ra = ra < N ? ra : N - 1;
      rb = rb < N ? rb : N - 1;
      h8 A0 = *(const h8*)(Xa + ra * DFEAT + kk);
      h8 A1 = *(const h8*)(Xa + rb * DFEAT + kk);
      #pragma unroll
      for (int ct = 0; ct < 4; ++ct) {
        h8 B = *(const h8*)(Wl + (l16 + 16 * ct) * 264 + (s << 5) + (lq << 3));
        acc[0][ct] = __builtin_amdgcn_mfma_f32_16x16x32_f16(A0, B, acc[0][ct], 0, 0, 0);
        acc[1][ct] = __builtin_amdgcn_mfma_f32_16x16x32_f16(A1, B, acc[1][ct], 0, 0, 0);
      }
    }

    #pragma unroll
    for (int rt = 0; rt < 2; ++rt) {
      #pragma unroll
      for (int ct = 0; ct < 4; ++ct) {
        int col = 16 * ct + l16;
        float bb = b[col];
        #pragma unroll
        for (int reg = 0; reg < 4; ++reg) {
          long long row = r0 + rt * 16 + lq * 4 + reg;
          if (row < N) {
            float v = acc[rt][ct][reg] + bb + (float)resid[row * DFEAT + col];
            v = v > 0.f ? v : LSLOPE * v;
            if (OUTF16) ((_Float16*)outp)[row * DFEAT + col] = (_Float16)v;
            else        ((float*)outp)[row * DFEAT + col] = v;
          }
        }
      }
    }
  }
}

// ---------------------------------------------------------------- mega kernel
// All 8 compute phases in one cooperative launch: 6 spmm + 2 combine with
// grid.sync() between (replaces 7 inter-dispatch gaps of ~4us with ~2us syncs).
// __launch_bounds__(256,4): 4 waves/EU -> VGPR<=128 -> 4 blocks/CU guaranteed
// co-resident with the 33.8KB LDS (135KB/CU of 160). No early returns.
__global__ void __launch_bounds__(256, 4) mega_kernel(
    const _Float16* xh, _Float16* h1, _Float16* h2b, _Float16* h3, _Float16* o1,
    float* out, const _Float16* Wt, const float* b1, const float* b2,
    const int* rowptr, const unsigned* ep, int N) {
  cg::grid_group grid = cg::this_grid();
  __shared__ __align__(16) _Float16 Wl[64 * 264];   // 33792 B

  // layer 1
  spmm_phase(xh, rowptr, ep, h1, N);
  grid.sync();
  spmm_phase(h1, rowptr, ep, h2b, N);
  grid.sync();
  spmm_phase(h2b, rowptr, ep, h3, N);
  grid.sync();
  combine_phase<1>(Wl, xh, h1, h2b, h3, Wt, b1, xh, o1, N);
  grid.sync();
  // layer 2
  spmm_phase(o1, rowptr, ep, h1, N);
  grid.sync();
  spmm_phase(h1, rowptr, ep, h2b, N);
  grid.sync();
  spmm_phase(h2b, rowptr, ep, h3, N);
  grid.sync();
  combine_phase<0>(Wl, o1, h1, h2b, h3, Wt + 64 * 264, b2, o1, out, N);
}

// ---------------------------------------------------------------- launch
extern "C" void kernel_launch(void* const* d_in, const int* in_sizes, int n_in,
                              void* d_out, int out_size, void* d_ws, size_t ws_size,
                              hipStream_t stream) {
  const float* y  = (const float*)d_in[0];
  const void*  ei = d_in[1];
  const float* ew = (const float*)d_in[2];
  const float* W1 = (const float*)d_in[3];
  const float* b1 = (const float*)d_in[4];
  const float* W2 = (const float*)d_in[5];
  const float* b2 = (const float*)d_in[6];
  float* out = (float*)d_out;

  const int N = in_sizes[0] / DFEAT;
  const int E = in_sizes[2];
  const size_t ND = (size_t)N * DFEAT;
  const int nbins = (N + (1 << BINSHIFT) - 1) >> BINSHIFT;   // <= 256

  _Float16* xh = (_Float16*)d_ws;
  _Float16* h1 = xh + ND;
  _Float16* h2b = h1 + ND;
  _Float16* h3 = h2b + ND;
  _Float16* o1 = h3 + ND;
  _Float16* Wt = o1 + ND;               // 2 * 64*264 f16
  int* rowptr   = (int*)(((uintptr_t)(Wt + 2 * 64 * 264) + 255) & ~(uintptr_t)255);
  int* binCnt   = rowptr + (N + 1);
  int* flag     = binCnt + 256;
  int2* bins    = (int2*)(((uintptr_t)(flag + 1) + 255) & ~(uintptr_t)255);
  unsigned* ep  = (unsigned*)(bins + (size_t)nbins * BINCAP);

  const int n4 = (int)(ND / 4);
  const int cp_total = n4 + 2 * 64 * 264;

  setup_kernel<<<1, 256, 0, stream>>>((const unsigned int*)ei, flag, binCnt);
  cvtprep_kernel<<<(cp_total + 255) / 256, 256, 0, stream>>>(y, xh, n4, W1, W2, Wt);
  binA_kernel<<<(E + CHUNK - 1) / CHUNK, 256, 0, stream>>>(ei, ew, E, flag, binCnt, bins, nbins);
  binB_kernel<<<nbins, 256, 0, stream>>>(bins, binCnt, rowptr, ep, nbins, N);

  // cooperative mega-kernel: grid capped by queried occupancy (all blocks
  // must be co-resident for grid.sync)
  int maxb = 4;
  hipOccupancyMaxActiveBlocksPerMultiprocessor(&maxb, (const void*)mega_kernel, 256, 0);
  if (maxb < 1) maxb = 1;
  long long mg = (long long)maxb * 256;
  if (mg > 1024) mg = 1024;
  int grid = (int)mg;

  void* kargs[] = {(void*)&xh, (void*)&h1, (void*)&h2b, (void*)&h3, (void*)&o1,
                   (void*)&out, (void*)&Wt, (void*)&b1, (void*)&b2,
                   (void*)&rowptr, (void*)&ep, (void*)&N};
  hipLaunchCooperativeKernel((const void*)mega_kernel, dim3(grid), dim3(256),
                             kargs, 0, stream);
}

// Round 16
// 223.506 us; speedup vs baseline: 3.4428x; 3.4428x over previous
//
#include <hip/hip_runtime.h>
#include <cstdint>
#include <cstddef>

#define DFEAT 64
#define LSLOPE 0.01f
#define BINSHIFT 9          // 512 nodes per bin
#define BINCAP 6144         // mean ~5120 edges/bin, +14 sigma margin
#define CHUNK 4096

typedef _Float16 h8 __attribute__((ext_vector_type(8)));
typedef _Float16 h4 __attribute__((ext_vector_type(4)));
typedef _Float16 h2 __attribute__((ext_vector_type(2)));
typedef float f4 __attribute__((ext_vector_type(4)));

// ---------------------------------------------------------------- cvt + W-prep + setup
// [0, n4): x f32 -> f16 (float4-wide). [n4, n4+2*64*264): build Wt with
// Wt[layer][c][64a+k] = W[a][k][c], padded row stride 264.
// Block 0 additionally: dtype-detect edge_index (int64 vs silently-int32 from
// jax -- node ids < 2^31 so for int64 data every odd 32-bit word of the first
// 1024 values is 0) and zero binCnt. Absorbs the old setup_kernel dispatch.
__global__ void cvtprep_kernel(const float* __restrict__ in, _Float16* __restrict__ out,
                               int n4, const float* __restrict__ W1,
                               const float* __restrict__ W2, _Float16* __restrict__ Wt,
                               const unsigned int* __restrict__ ei, int* flag,
                               int* __restrict__ binCnt) {
  if (blockIdx.x == 0) {
    __shared__ int cnt;
    if (threadIdx.x == 0) cnt = 0;
    binCnt[threadIdx.x] = 0;
    __syncthreads();
    int z = 0;
    for (int i = threadIdx.x; i < 1024; i += blockDim.x)
      z += (ei[2 * i + 1] == 0u) ? 1 : 0;
    atomicAdd(&cnt, z);
    __syncthreads();
    if (threadIdx.x == 0) *flag = (cnt == 1024) ? 1 : 0;
  }
  int i = blockIdx.x * blockDim.x + threadIdx.x;
  if (i < n4) {
    float4 v = ((const float4*)in)[i];
    h4 o;
    o[0] = (_Float16)v.x; o[1] = (_Float16)v.y;
    o[2] = (_Float16)v.z; o[3] = (_Float16)v.w;
    ((h4*)out)[i] = o;
  } else {
    int t = i - n4;
    if (t < 2 * 64 * 264) {
      int layer = t / (64 * 264);
      int r = t % (64 * 264);
      int c = r / 264;
      int kg = r % 264;
      float v = 0.f;
      if (kg < 256) {
        const float* W = layer ? W2 : W1;
        int a = kg >> 6, k = kg & 63;
        v = W[a * 4096 + k * 64 + c];
      }
      Wt[t] = (_Float16)v;
    }
  }
}

// ---------------------------------------------------------------- binned CSR build
// Phase A: per-workgroup LDS counting sort of a 4096-edge chunk into <=256
// coarse bins (dst>>9); dense contiguous appends per bin.
__global__ __launch_bounds__(256) void binA_kernel(
    const void* __restrict__ ei, const float* __restrict__ ew, int E,
    const int* __restrict__ flag, int* __restrict__ binCnt,
    int2* __restrict__ bins, int nbins) {
  __shared__ int hist[256];
  __shared__ int pref[256];
  __shared__ int lofs[256];
  __shared__ int gbase[256];
  __shared__ int2 pairs[CHUNK];   // 32 KB
  int tid = threadIdx.x;
  int base = blockIdx.x * CHUNK;
  int nedge = E - base; if (nedge > CHUNK) nedge = CHUNK;
  for (int i = tid; i < nbins; i += 256) hist[i] = 0;
  __syncthreads();
  const bool is64 = (*flag != 0);
  for (int j = tid; j < nedge; j += 256) {
    int e = base + j;
    int d = is64 ? (int)((const long long*)ei)[(size_t)E + e]
                 : ((const int*)ei)[(size_t)E + e];
    atomicAdd(&hist[d >> BINSHIFT], 1);
  }
  __syncthreads();
  if (tid == 0) {
    int run = 0;
    for (int b = 0; b < nbins; ++b) { pref[b] = run; lofs[b] = run; run += hist[b]; }
  }
  __syncthreads();
  for (int j = tid; j < nedge; j += 256) {
    int e = base + j;
    int s, d;
    if (is64) { const long long* p = (const long long*)ei; s = (int)p[e]; d = (int)p[(size_t)E + e]; }
    else      { const int* p = (const int*)ei; s = p[e]; d = p[(size_t)E + e]; }
    int wq = (int)(ew[e] * 32768.0f + 0.5f);
    wq = wq > 32767 ? 32767 : wq;
    unsigned P = ((unsigned)s << 15) | (unsigned)wq;
    int pos = atomicAdd(&lofs[d >> BINSHIFT], 1);
    pairs[pos] = make_int2((int)P, d);
  }
  __syncthreads();
  for (int b = tid; b < nbins; b += 256)
    gbase[b] = (hist[b] > 0) ? atomicAdd(&binCnt[b], hist[b]) : 0;
  __syncthreads();
  for (int i = tid; i < nedge; i += 256) {
    int2 pr = pairs[i];
    int b = pr.y >> BINSHIFT;
    int off = gbase[b] + (i - pref[b]);
    if (off < BINCAP) bins[(size_t)b * BINCAP + off] = pr;
  }
}

// Phase B: one workgroup per bin; in-block scan of binCnt -> LDS counting
// sort -> rowptr + final ep.
__global__ __launch_bounds__(256) void binB_kernel(
    const int2* __restrict__ bins, const int* __restrict__ binCnt,
    int* __restrict__ rowptr, unsigned* __restrict__ ep, int nbins, int N) {
  __shared__ int ssum[256];
  __shared__ int cnt[512];
  __shared__ int ofs[512];
  int b = blockIdx.x, tid = threadIdx.x;
  ssum[tid] = (tid < nbins) ? binCnt[tid] : 0;
  __syncthreads();
  for (int off = 1; off < 256; off <<= 1) {
    int val = ssum[tid];
    int add = (tid >= off) ? ssum[tid - off] : 0;
    __syncthreads();
    ssum[tid] = val + add;
    __syncthreads();
  }
  int gstart = (b == 0) ? 0 : ssum[b - 1];
  if (b == nbins - 1 && tid == 0) rowptr[N] = ssum[nbins - 1];
  int nb = binCnt[b]; if (nb > BINCAP) nb = BINCAP;
  int dstBase = b << BINSHIFT;
  const int2* mybin = bins + (size_t)b * BINCAP;
  for (int i = tid; i < 512; i += 256) cnt[i] = 0;
  __syncthreads();
  for (int i = tid; i < nb; i += 256)
    atomicAdd(&cnt[mybin[i].y & 511], 1);
  __syncthreads();
  if (tid == 0) {
    int run = gstart;
    for (int k = 0; k < 512; ++k) { ofs[k] = run; run += cnt[k]; }
  }
  __syncthreads();
  for (int k = tid; k < 512; k += 256) {
    int d = dstBase + k;
    if (d < N) rowptr[d] = ofs[k];
  }
  __syncthreads();   // rowptr reads of ofs must complete before scatter mutates
  for (int i = tid; i < nb; i += 256) {
    int2 pr = mybin[i];
    int pos = atomicAdd(&ofs[pr.y & 511], 1);
    ep[pos] = (unsigned)pr.x;
  }
}

// ---------------------------------------------------------------- SpMM (CSR, f16)
// 8-lane group = one node; lane owns a feature octet (uint4 = 8 f16 = 16B).
// Packed-f16 accumulation (v_pk_fma_f16, ~7 VALU/edge). Mov-free modulo-4
// schedule: 4 NAMED slots, each iteration consumes a slot then reloads it IN
// PLACE (no register rotation). Converged across r11/r12/r13 at ~22us =
// ~5.8 TB/s aggregate gather delivery (~92% of achievable).
__device__ __forceinline__ void edge_fma(unsigned p, const uint4& v, float qs,
                                         h2& acc0, h2& acc1, h2& acc2, h2& acc3) {
  _Float16 wh = (_Float16)((float)(p & 32767u) * qs);
  h2 wp = {wh, wh};
  union { uint32_t u; h2 h; } cx, cy, cz, cw;
  cx.u = v.x; cy.u = v.y; cz.u = v.z; cw.u = v.w;
  acc0 += wp * cx.h; acc1 += wp * cy.h;
  acc2 += wp * cz.h; acc3 += wp * cw.h;
}

__global__ __launch_bounds__(256) void spmm_kernel(
    const _Float16* __restrict__ x, const int* __restrict__ rowptr,
    const unsigned* __restrict__ ep, _Float16* __restrict__ hout, int N) {
  int node = blockIdx.x * 32 + (threadIdx.x >> 3);
  if (node >= N) return;
  int fo = threadIdx.x & 7;           // feature octet: feats 8fo..8fo+7
  int beg = rowptr[node], end = rowptr[node + 1];
  const float qs = 1.0f / 32768.0f;
  const uint4* __restrict__ xu = (const uint4*)x;   // row stride 8 uint4
  h2 acc0 = {0, 0}, acc1 = {0, 0}, acc2 = {0, 0}, acc3 = {0, 0};
  int n = end - beg;
  if (n >= 4) {
    unsigned pa = ep[beg], pb = ep[beg + 1], pc = ep[beg + 2], pd = ep[beg + 3];
    uint4 va = xu[(size_t)(pa >> 15) * 8 + fo];
    uint4 vb = xu[(size_t)(pb >> 15) * 8 + fo];
    uint4 vc = xu[(size_t)(pc >> 15) * 8 + fo];
    uint4 vd = xu[(size_t)(pd >> 15) * 8 + fo];
    int i = beg + 4;
    for (; i + 3 < end; i += 4) {
      edge_fma(pa, va, qs, acc0, acc1, acc2, acc3);
      pa = ep[i];     va = xu[(size_t)(pa >> 15) * 8 + fo];
      edge_fma(pb, vb, qs, acc0, acc1, acc2, acc3);
      pb = ep[i + 1]; vb = xu[(size_t)(pb >> 15) * 8 + fo];
      edge_fma(pc, vc, qs, acc0, acc1, acc2, acc3);
      pc = ep[i + 2]; vc = xu[(size_t)(pc >> 15) * 8 + fo];
      edge_fma(pd, vd, qs, acc0, acc1, acc2, acc3);
      pd = ep[i + 3]; vd = xu[(size_t)(pd >> 15) * 8 + fo];
    }
    edge_fma(pa, va, qs, acc0, acc1, acc2, acc3);
    edge_fma(pb, vb, qs, acc0, acc1, acc2, acc3);
    edge_fma(pc, vc, qs, acc0, acc1, acc2, acc3);
    edge_fma(pd, vd, qs, acc0, acc1, acc2, acc3);
    for (; i < end; ++i) {
      unsigned p = ep[i];
      uint4 v = xu[(size_t)(p >> 15) * 8 + fo];
      edge_fma(p, v, qs, acc0, acc1, acc2, acc3);
    }
  } else {
    for (int i = beg; i < end; ++i) {
      unsigned p = ep[i];
      uint4 v = xu[(size_t)(p >> 15) * 8 + fo];
      edge_fma(p, v, qs, acc0, acc1, acc2, acc3);
    }
  }
  union { uint4 u; h2 h[4]; } o;
  o.h[0] = acc0; o.h[1] = acc1; o.h[2] = acc2; o.h[3] = acc3;
  ((uint4*)hout)[(size_t)node * 8 + fo] = o.u;
}

// ---------------------------------------------------------------- MFMA combine
// out = leaky_relu( [x|h1|h2|h3] @ Wcat + b + resid ), K=256 -> 64.
// At its traffic floor: ~12.3MB read + write per dispatch.
template <int OUTF16>
__global__ __launch_bounds__(256) void combine_mfma_kernel(
    const _Float16* __restrict__ x0, const _Float16* __restrict__ h1,
    const _Float16* __restrict__ h2v, const _Float16* __restrict__ h3,
    const _Float16* __restrict__ Wt, const float* __restrict__ b,
    const _Float16* __restrict__ resid, void* __restrict__ outp, int N) {
  __shared__ __align__(16) _Float16 Wl[64 * 264];   // 33792 B

  int tid = threadIdx.x;
  {
    const uint32_t* g = (const uint32_t*)Wt;
    uint32_t* l = (uint32_t*)Wl;
    for (int i = tid; i < 64 * 132; i += 256) l[i] = g[i];
  }
  __syncthreads();

  int w = tid >> 6, lane = tid & 63;
  int l16 = lane & 15, lq = lane >> 4;
  int r0 = blockIdx.x * 128 + w * 32;

  f4 acc[2][4];
  f4 zero = {0.f, 0.f, 0.f, 0.f};
  #pragma unroll
  for (int rt = 0; rt < 2; ++rt)
    #pragma unroll
    for (int ct = 0; ct < 4; ++ct) acc[rt][ct] = zero;

  const _Float16* hops[4] = {x0, h1, h2v, h3};

  #pragma unroll
  for (int s = 0; s < 8; ++s) {
    const _Float16* __restrict__ Xa = hops[s >> 1];
    int kk = ((s & 1) << 5) + (lq << 3);
    int ra = r0 + l16;
    int rb = ra + 16;
    ra = ra < N ? ra : N - 1;
    rb = rb < N ? rb : N - 1;
    h8 A0 = *(const h8*)(Xa + (size_t)ra * DFEAT + kk);
    h8 A1 = *(const h8*)(Xa + (size_t)rb * DFEAT + kk);
    #pragma unroll
    for (int ct = 0; ct < 4; ++ct) {
      h8 B = *(const h8*)(Wl + (l16 + 16 * ct) * 264 + (s << 5) + (lq << 3));
      acc[0][ct] = __builtin_amdgcn_mfma_f32_16x16x32_f16(A0, B, acc[0][ct], 0, 0, 0);
      acc[1][ct] = __builtin_amdgcn_mfma_f32_16x16x32_f16(A1, B, acc[1][ct], 0, 0, 0);
    }
  }

  #pragma unroll
  for (int rt = 0; rt < 2; ++rt) {
    #pragma unroll
    for (int ct = 0; ct < 4; ++ct) {
      int col = 16 * ct + l16;
      float bb = b[col];
      #pragma unroll
      for (int reg = 0; reg < 4; ++reg) {
        int row = r0 + rt * 16 + lq * 4 + reg;
        if (row < N) {
          float v = acc[rt][ct][reg] + bb + (float)resid[(size_t)row * DFEAT + col];
          v = v > 0.f ? v : LSLOPE * v;
          if (OUTF16) ((_Float16*)outp)[(size_t)row * DFEAT + col] = (_Float16)v;
          else        ((float*)outp)[(size_t)row * DFEAT + col] = v;
        }
      }
    }
  }
}

// ---------------------------------------------------------------- launch
extern "C" void kernel_launch(void* const* d_in, const int* in_sizes, int n_in,
                              void* d_out, int out_size, void* d_ws, size_t ws_size,
                              hipStream_t stream) {
  const float* y  = (const float*)d_in[0];
  const void*  ei = d_in[1];
  const float* ew = (const float*)d_in[2];
  const float* W1 = (const float*)d_in[3];
  const float* b1 = (const float*)d_in[4];
  const float* W2 = (const float*)d_in[5];
  const float* b2 = (const float*)d_in[6];
  float* out = (float*)d_out;

  const int N = in_sizes[0] / DFEAT;
  const int E = in_sizes[2];
  const size_t ND = (size_t)N * DFEAT;
  const int nbins = (N + (1 << BINSHIFT) - 1) >> BINSHIFT;   // <= 256

  _Float16* xh = (_Float16*)d_ws;
  _Float16* h1 = xh + ND;
  _Float16* h2b = h1 + ND;
  _Float16* h3 = h2b + ND;
  _Float16* o1 = h3 + ND;
  _Float16* Wt = o1 + ND;               // 2 * 64*264 f16
  int* rowptr   = (int*)(((uintptr_t)(Wt + 2 * 64 * 264) + 255) & ~(uintptr_t)255);
  int* binCnt   = rowptr + (N + 1);
  int* flag     = binCnt + 256;
  int2* bins    = (int2*)(((uintptr_t)(flag + 1) + 255) & ~(uintptr_t)255);
  unsigned* ep  = (unsigned*)(bins + (size_t)nbins * BINCAP);

  const int n4 = (int)(ND / 4);
  const int cp_total = n4 + 2 * 64 * 264;

  cvtprep_kernel<<<(cp_total + 255) / 256, 256, 0, stream>>>(
      y, xh, n4, W1, W2, Wt, (const unsigned int*)ei, flag, binCnt);
  binA_kernel<<<(E + CHUNK - 1) / CHUNK, 256, 0, stream>>>(ei, ew, E, flag, binCnt, bins, nbins);
  binB_kernel<<<nbins, 256, 0, stream>>>(bins, binCnt, rowptr, ep, nbins, N);

  const int spmm_grid = (N + 31) / 32;
  const int comb_grid = (N + 127) / 128;

  // layer 1
  spmm_kernel<<<spmm_grid, 256, 0, stream>>>(xh, rowptr, ep, h1, N);
  spmm_kernel<<<spmm_grid, 256, 0, stream>>>(h1, rowptr, ep, h2b, N);
  spmm_kernel<<<spmm_grid, 256, 0, stream>>>(h2b, rowptr, ep, h3, N);
  combine_mfma_kernel<1><<<comb_grid, 256, 0, stream>>>(xh, h1, h2b, h3, Wt, b1, xh, o1, N);
  // layer 2
  spmm_kernel<<<spmm_grid, 256, 0, stream>>>(o1, rowptr, ep, h1, N);
  spmm_kernel<<<spmm_grid, 256, 0, stream>>>(h1, rowptr, ep, h2b, N);
  spmm_kernel<<<spmm_grid, 256, 0, stream>>>(h2b, rowptr, ep, h3, N);
  combine_mfma_kernel<0><<<comb_grid, 256, 0, stream>>>(o1, h1, h2b, h3, Wt + 64 * 264, b2, o1, out, N);
}